// Round 10
// baseline (685.176 us; speedup 1.0000x reference)
//
#include <hip/hip_runtime.h>
#include <math.h>

#define NN 50000
#define NE 800000
#define IND 256
#define NH 64
#define DEPTH 4
#define PART_DIV 6250   // ceil(NN/8): node partition for XCD-local scatter
#define SB 49           // scan blocks per array (49*1024 >= NN)
#define EPP 100000      // edges per count partition (NE/8)

// ---------------- bf16 helpers ----------------

__device__ __forceinline__ unsigned short f2bf(float f) {
    unsigned int x = __float_as_uint(f);
    unsigned int r = (x + 0x7fffu + ((x >> 16) & 1u)) >> 16;
    return (unsigned short)r;
}
__device__ __forceinline__ unsigned int pack2bf(float lo, float hi) {
    return (unsigned int)f2bf(lo) | ((unsigned int)f2bf(hi) << 16);
}
__device__ __forceinline__ ushort4 f4_to_us4(float4 f) {
    ushort4 u;
    u.x = f2bf(f.x); u.y = f2bf(f.y); u.z = f2bf(f.z); u.w = f2bf(f.w);
    return u;
}
__device__ __forceinline__ void acc8(float* a, uint4 r) {
    a[0] += __uint_as_float(r.x << 16); a[1] += __uint_as_float(r.x & 0xffff0000u);
    a[2] += __uint_as_float(r.y << 16); a[3] += __uint_as_float(r.y & 0xffff0000u);
    a[4] += __uint_as_float(r.z << 16); a[5] += __uint_as_float(r.z & 0xffff0000u);
    a[6] += __uint_as_float(r.w << 16); a[7] += __uint_as_float(r.w & 0xffff0000u);
}
__device__ __forceinline__ void unpack8(float* a, uint4 r) {
    a[0] = __uint_as_float(r.x << 16); a[1] = __uint_as_float(r.x & 0xffff0000u);
    a[2] = __uint_as_float(r.y << 16); a[3] = __uint_as_float(r.y & 0xffff0000u);
    a[4] = __uint_as_float(r.z << 16); a[5] = __uint_as_float(r.z & 0xffff0000u);
    a[6] = __uint_as_float(r.w << 16); a[7] = __uint_as_float(r.w & 0xffff0000u);
}
__device__ __forceinline__ void accd8(float* a, const float* xg, uint4 r) {
    float e;
    e = xg[0] - __uint_as_float(r.x << 16);         a[0] += e * e;
    e = xg[1] - __uint_as_float(r.x & 0xffff0000u); a[1] += e * e;
    e = xg[2] - __uint_as_float(r.y << 16);         a[2] += e * e;
    e = xg[3] - __uint_as_float(r.y & 0xffff0000u); a[3] += e * e;
    e = xg[4] - __uint_as_float(r.z << 16);         a[4] += e * e;
    e = xg[5] - __uint_as_float(r.z & 0xffff0000u); a[5] += e * e;
    e = xg[6] - __uint_as_float(r.w << 16);         a[6] += e * e;
    e = xg[7] - __uint_as_float(r.w & 0xffff0000u); a[7] += e * e;
}
__device__ __forceinline__ float tanh_pos(float x) {
    float t = __expf(-2.f * x);
    return (1.f - t) / (1.f + t);
}

// ---------------- CSR build ----------------

// XCD-private histogram count: partition p (blockIdx&7 -> XCD p) counts edge
// range [p*EPP,(p+1)*EPP) into its OWN histograms hin[p],hout[p]. Atomics stay
// in one XCD's L2 (no cross-XCD line ping-pong). The atomic return is the
// partition-LOCAL rank, stored densely (coalesced).
__global__ void count8(const int* __restrict__ src, const int* __restrict__ dst,
                       int* __restrict__ hin, int* __restrict__ hout,
                       int* __restrict__ lrin, int* __restrict__ lrout,
                       int nGroups) {
    int p = blockIdx.x & 7;
    int g = blockIdx.x >> 3;
    int* hi = hin + p * NN;
    int* ho = hout + p * NN;
    for (int i = g * 256 + threadIdx.x; i < EPP; i += nGroups * 256) {
        int e = p * EPP + i;
        int s = src[e], d = dst[e];
        lrin[e]  = atomicAdd(&hi[d], 1);
        lrout[e] = atomicAdd(&ho[s], 1);
    }
}

// reduce: degin[i] = sum_p hin[p][i]; hin[p][i] <- exclusive base over p.
__global__ void reduce8(int* __restrict__ hin, int* __restrict__ hout,
                        int* __restrict__ degin, int* __restrict__ degout) {
    int i = blockIdx.x * blockDim.x + threadIdx.x;
    if (i >= NN) return;
    int run = 0;
#pragma unroll
    for (int p = 0; p < 8; ++p) {
        int t = hin[p * NN + i]; hin[p * NN + i] = run; run += t;
    }
    degin[i] = run;
    run = 0;
#pragma unroll
    for (int p = 0; p < 8; ++p) {
        int t = hout[p * NN + i]; hout[p * NN + i] = run; run += t;
    }
    degout[i] = run;
}

// -------- parallel exclusive scan, 3 phases, two arrays at once --------
__global__ __launch_bounds__(512) void scan_p1(const int* __restrict__ in0,
                                               const int* __restrict__ in1,
                                               int* __restrict__ tmp,
                                               int* __restrict__ bsum) {
    int a = blockIdx.x / SB;
    int b = blockIdx.x % SB;
    const int* in = a ? in1 : in0;
    int t = threadIdx.x;
    int base = b * 1024 + t * 2;
    int v0 = (base < NN) ? in[base] : 0;
    int v1 = (base + 1 < NN) ? in[base + 1] : 0;
    int v = v0 + v1;
    int x = v;
#pragma unroll
    for (int off = 1; off < 64; off <<= 1) {
        int u = __shfl_up(x, off);
        if ((t & 63) >= off) x += u;
    }
    __shared__ int ws[8];
    int wid = t >> 6, lane = t & 63;
    if (lane == 63) ws[wid] = x;
    __syncthreads();
    if (t == 0) {
        int run = 0;
#pragma unroll
        for (int w = 0; w < 8; ++w) { int s = ws[w]; ws[w] = run; run += s; }
    }
    __syncthreads();
    x += ws[wid];              // inclusive over block
    int excl = x - v;
    if (base < NN) tmp[a * NN + base] = excl;
    if (base + 1 < NN) tmp[a * NN + base + 1] = excl + v0;
    if (t == 511) bsum[a * SB + b] = x;   // block total
}

__global__ __launch_bounds__(128) void scan_p2(int* __restrict__ bsum,
                                               int* __restrict__ out0,
                                               int* __restrict__ out1) {
    int t = threadIdx.x;
    int a = t >> 6, lane = t & 63;
    int v = (lane < SB) ? bsum[a * SB + lane] : 0;
    int x = v;
#pragma unroll
    for (int off = 1; off < 64; off <<= 1) {
        int u = __shfl_up(x, off);
        if (lane >= off) x += u;
    }
    if (lane < SB) bsum[a * SB + lane] = x - v;   // exclusive
    if (lane == SB - 1) {
        if (a == 0) out0[NN] = x; else out1[NN] = x;
    }
}

__global__ __launch_bounds__(512) void scan_p3(const int* __restrict__ tmp,
                                               const int* __restrict__ bsum,
                                               int* __restrict__ out0,
                                               int* __restrict__ out1) {
    int a = blockIdx.x / SB;
    int b = blockIdx.x % SB;
    int* out = a ? out1 : out0;
    int add = bsum[a * SB + b];
    int t = threadIdx.x;
    int base = b * 1024 + t * 2;
    if (base < NN) out[base] = tmp[a * NN + base] + add;
    if (base + 1 < NN) out[base + 1] = tmp[a * NN + base + 1] + add;
}

__global__ void init_node(const int* __restrict__ degin, const int* __restrict__ degout,
                          float* __restrict__ dis, float* __restrict__ cntf) {
    int i = blockIdx.x * blockDim.x + threadIdx.x;
    if (i < NN) {
        dis[i] = rsqrtf((float)(degin[i] + 1));   // +1 self loop; always >0
        int od = degout[i];
        cntf[i] = (float)(od > 0 ? od : 1);
    }
}

// Atomic-free, XCD-partitioned scatter. Global rank = partition base + local
// rank. Store partition q (blockIdx&7) only writes CSR slices of its node
// range -> stores stay L2-local.
__global__ void fill_csr_part(const int* __restrict__ src, const int* __restrict__ dst,
                              const int* __restrict__ off_dst, const int* __restrict__ off_src,
                              const int* __restrict__ hin, const int* __restrict__ hout,
                              const int* __restrict__ lrin, const int* __restrict__ lrout,
                              int* __restrict__ srcs_by_dst, int* __restrict__ dsts_by_src,
                              int nGroups) {
    int q = blockIdx.x & 7;
    int g = blockIdx.x >> 3;
    for (int pe = 0; pe < 8; ++pe) {
        const int* bin = hin + pe * NN;
        const int* bout = hout + pe * NN;
        for (int i = g * 256 + threadIdx.x; i < EPP; i += nGroups * 256) {
            int e = pe * EPP + i;
            int s = src[e], d = dst[e];
            if (d / PART_DIV == q) srcs_by_dst[off_dst[d] + bin[d] + lrin[e]] = s;
            if (s / PART_DIV == q) dsts_by_src[off_src[s] + bout[s] + lrout[e]] = d;
        }
    }
}

// ---------------- GEMM: [n,K] @ [K,64], 64 rows per block (enc/dec) ----------------
template<int K, bool RELU, bool WSC>
__global__ __launch_bounds__(256) void gemm64b(const float* __restrict__ X,
                                               const float* __restrict__ W,
                                               const float* __restrict__ bias,
                                               const float* __restrict__ rowscale,
                                               float* __restrict__ out,
                                               unsigned short* __restrict__ xsc, int n) {
    __shared__ float Ws[64 * 64];
    __shared__ float Xs[64][68];
    int tid = threadIdx.x;
    int row0 = blockIdx.x * 64;
    int r16 = tid >> 4;
    int cg = tid & 15;
    float4 acc[4];
#pragma unroll
    for (int t = 0; t < 4; ++t) acc[t] = make_float4(0.f, 0.f, 0.f, 0.f);

    for (int kc = 0; kc < K; kc += 64) {
        const float4* W4 = (const float4*)(W + (size_t)kc * 64);
        float4* Ws4 = (float4*)Ws;
#pragma unroll
        for (int t = 0; t < 4; ++t) Ws4[tid + t * 256] = W4[tid + t * 256];
#pragma unroll
        for (int t = 0; t < 4; ++t) {
            int r = r16 + t * 16;
            int grow = row0 + r;
            float4 xv = make_float4(0.f, 0.f, 0.f, 0.f);
            if (grow < n) xv = *(const float4*)(X + (size_t)grow * K + kc + cg * 4);
            Xs[r][cg * 4 + 0] = xv.x; Xs[r][cg * 4 + 1] = xv.y;
            Xs[r][cg * 4 + 2] = xv.z; Xs[r][cg * 4 + 3] = xv.w;
        }
        __syncthreads();
#pragma unroll
        for (int k = 0; k < 64; ++k) {
            float4 w4 = ((const float4*)Ws)[k * 16 + cg];
#pragma unroll
            for (int t = 0; t < 4; ++t) {
                float xv = Xs[r16 + t * 16][k];
                acc[t].x += xv * w4.x; acc[t].y += xv * w4.y;
                acc[t].z += xv * w4.z; acc[t].w += xv * w4.w;
            }
        }
        __syncthreads();
    }

    float4 b4 = ((const float4*)bias)[cg];
#pragma unroll
    for (int t = 0; t < 4; ++t) {
        int row = row0 + r16 + t * 16;
        if (row < n) {
            float4 o;
            o.x = acc[t].x + b4.x; o.y = acc[t].y + b4.y;
            o.z = acc[t].z + b4.z; o.w = acc[t].w + b4.w;
            if (RELU) {
                o.x = fmaxf(o.x, 0.f); o.y = fmaxf(o.y, 0.f);
                o.z = fmaxf(o.z, 0.f); o.w = fmaxf(o.w, 0.f);
            }
            ((float4*)(out + (size_t)row * 64))[cg] = o;
            if (WSC) {
                float s = rowscale[row];
                float4 o2 = make_float4(o.x * s, o.y * s, o.z * s, o.w * s);
                ((ushort4*)(xsc + (size_t)row * 64))[cg] = f4_to_us4(o2);
            }
        }
    }
}

// ---------------- gemm64z: [n,64] @ [64,64] + relu, fp32 or bf16 out ----------------
template<bool OUTBF>
__global__ __launch_bounds__(256) void gemm64z(const float* __restrict__ Z,
                                               const float* __restrict__ W,
                                               const float* __restrict__ bias,
                                               float* __restrict__ outf,
                                               unsigned short* __restrict__ outb, int n) {
    __shared__ float Ws[64 * 64];
    __shared__ float Xs[64][68];
    int tid = threadIdx.x;
    int row0 = blockIdx.x * 64;
    int r16 = tid >> 4;
    int cg = tid & 15;
    float4 acc[4];
#pragma unroll
    for (int t = 0; t < 4; ++t) acc[t] = make_float4(0.f, 0.f, 0.f, 0.f);

    {
        const float4* W4 = (const float4*)W;
        float4* Ws4 = (float4*)Ws;
#pragma unroll
        for (int t = 0; t < 4; ++t) Ws4[tid + t * 256] = W4[tid + t * 256];
#pragma unroll
        for (int t = 0; t < 4; ++t) {
            int r = r16 + t * 16;
            int gr = row0 + r;
            float4 xv = make_float4(0.f, 0.f, 0.f, 0.f);
            if (gr < n) xv = *(const float4*)(Z + (size_t)gr * 64 + cg * 4);
            Xs[r][cg * 4 + 0] = xv.x; Xs[r][cg * 4 + 1] = xv.y;
            Xs[r][cg * 4 + 2] = xv.z; Xs[r][cg * 4 + 3] = xv.w;
        }
        __syncthreads();
#pragma unroll
        for (int k = 0; k < 64; ++k) {
            float4 w4 = ((const float4*)Ws)[k * 16 + cg];
#pragma unroll
            for (int t = 0; t < 4; ++t) {
                float xv = Xs[r16 + t * 16][k];
                acc[t].x += xv * w4.x; acc[t].y += xv * w4.y;
                acc[t].z += xv * w4.z; acc[t].w += xv * w4.w;
            }
        }
    }

    float4 b4 = ((const float4*)bias)[cg];
#pragma unroll
    for (int t = 0; t < 4; ++t) {
        int row = row0 + r16 + t * 16;
        if (row < n) {
            float4 o;
            o.x = fmaxf(acc[t].x + b4.x, 0.f); o.y = fmaxf(acc[t].y + b4.y, 0.f);
            o.z = fmaxf(acc[t].z + b4.z, 0.f); o.w = fmaxf(acc[t].w + b4.w, 0.f);
            if (OUTBF) {
                ((ushort4*)(outb + (size_t)row * 64))[cg] = f4_to_us4(o);
            } else {
                ((float4*)(outf + (size_t)row * 64))[cg] = o;
            }
        }
    }
}

// ---------------- zgather: node-per-octet, LDS-free, unroll 8 ----------------
// nbr indices: 1 coalesced load per lane + intra-octet shuffle broadcast
// (safe: all 8 lanes of an octet share identical loop bounds).
__global__ __launch_bounds__(256) void zgather(
    const unsigned short* __restrict__ Xbf,
    const int* __restrict__ off, const int* __restrict__ nbr,
    const float* __restrict__ dis, float* __restrict__ Z)
{
    int t = blockIdx.x * 256 + threadIdx.x;
    int node = t >> 3, l8 = t & 7;
    if (node >= NN) return;
    int lane = threadIdx.x & 63;
    int octbase = lane & ~7;
    const uint4* Xb = (const uint4*)Xbf;   // row = 8 uint4
    float a[8];
    unpack8(a, Xb[(size_t)node * 8 + l8]); // self (dis_i*X_i)
    int lo = off[node], hi = off[node + 1];
    int j = lo;
    for (; j + 7 < hi; j += 8) {
        int nv = nbr[j + l8];
        int s0 = __shfl(nv, octbase + 0), s1 = __shfl(nv, octbase + 1);
        int s2 = __shfl(nv, octbase + 2), s3 = __shfl(nv, octbase + 3);
        int s4 = __shfl(nv, octbase + 4), s5 = __shfl(nv, octbase + 5);
        int s6 = __shfl(nv, octbase + 6), s7 = __shfl(nv, octbase + 7);
        uint4 r0 = Xb[(size_t)s0 * 8 + l8];
        uint4 r1 = Xb[(size_t)s1 * 8 + l8];
        uint4 r2 = Xb[(size_t)s2 * 8 + l8];
        uint4 r3 = Xb[(size_t)s3 * 8 + l8];
        uint4 r4 = Xb[(size_t)s4 * 8 + l8];
        uint4 r5 = Xb[(size_t)s5 * 8 + l8];
        uint4 r6 = Xb[(size_t)s6 * 8 + l8];
        uint4 r7 = Xb[(size_t)s7 * 8 + l8];
        acc8(a, r0); acc8(a, r1); acc8(a, r2); acc8(a, r3);
        acc8(a, r4); acc8(a, r5); acc8(a, r6); acc8(a, r7);
    }
    for (; j + 3 < hi; j += 4) {
        int s0 = nbr[j], s1 = nbr[j + 1], s2 = nbr[j + 2], s3 = nbr[j + 3];
        uint4 r0 = Xb[(size_t)s0 * 8 + l8];
        uint4 r1 = Xb[(size_t)s1 * 8 + l8];
        uint4 r2 = Xb[(size_t)s2 * 8 + l8];
        uint4 r3 = Xb[(size_t)s3 * 8 + l8];
        acc8(a, r0); acc8(a, r1); acc8(a, r2); acc8(a, r3);
    }
    for (; j < hi; ++j) {
        acc8(a, Xb[(size_t)nbr[j] * 8 + l8]);
    }
    float di = dis[node];
    float* zp = Z + (size_t)node * 64 + l8 * 8;
    *(float4*)(zp)     = make_float4(di * a[0], di * a[1], di * a[2], di * a[3]);
    *(float4*)(zp + 4) = make_float4(di * a[4], di * a[5], di * a[6], di * a[7]);
}

// ---------------- gate + convex update: node-per-octet, LDS-free, unroll 8 ----------------
__global__ __launch_bounds__(256) void gate_update8(
    const unsigned short* __restrict__ Cbf, const float* __restrict__ Xn,
    float* __restrict__ X, unsigned short* __restrict__ Xbf,
    const int* __restrict__ off, const int* __restrict__ nbr,
    const float* __restrict__ cntf, const float* __restrict__ dis)
{
    int t = blockIdx.x * 256 + threadIdx.x;
    int node = t >> 3, l8 = t & 7;
    if (node >= NN) return;
    int lane = threadIdx.x & 63;
    int octbase = lane & ~7;
    const uint4* Cb = (const uint4*)Cbf;
    float xg[8];
    unpack8(xg, Cb[(size_t)node * 8 + l8]);
    float a[8] = {0.f, 0.f, 0.f, 0.f, 0.f, 0.f, 0.f, 0.f};
    int lo = off[node], hi = off[node + 1];
    int j = lo;
    for (; j + 7 < hi; j += 8) {
        int nv = nbr[j + l8];
        int d0 = __shfl(nv, octbase + 0), d1 = __shfl(nv, octbase + 1);
        int d2 = __shfl(nv, octbase + 2), d3 = __shfl(nv, octbase + 3);
        int d4 = __shfl(nv, octbase + 4), d5 = __shfl(nv, octbase + 5);
        int d6 = __shfl(nv, octbase + 6), d7 = __shfl(nv, octbase + 7);
        uint4 r0 = Cb[(size_t)d0 * 8 + l8];
        uint4 r1 = Cb[(size_t)d1 * 8 + l8];
        uint4 r2 = Cb[(size_t)d2 * 8 + l8];
        uint4 r3 = Cb[(size_t)d3 * 8 + l8];
        uint4 r4 = Cb[(size_t)d4 * 8 + l8];
        uint4 r5 = Cb[(size_t)d5 * 8 + l8];
        uint4 r6 = Cb[(size_t)d6 * 8 + l8];
        uint4 r7 = Cb[(size_t)d7 * 8 + l8];
        accd8(a, xg, r0); accd8(a, xg, r1); accd8(a, xg, r2); accd8(a, xg, r3);
        accd8(a, xg, r4); accd8(a, xg, r5); accd8(a, xg, r6); accd8(a, xg, r7);
    }
    for (; j + 3 < hi; j += 4) {
        int d0 = nbr[j], d1 = nbr[j + 1], d2 = nbr[j + 2], d3 = nbr[j + 3];
        uint4 r0 = Cb[(size_t)d0 * 8 + l8];
        uint4 r1 = Cb[(size_t)d1 * 8 + l8];
        uint4 r2 = Cb[(size_t)d2 * 8 + l8];
        uint4 r3 = Cb[(size_t)d3 * 8 + l8];
        accd8(a, xg, r0); accd8(a, xg, r1); accd8(a, xg, r2); accd8(a, xg, r3);
    }
    for (; j < hi; ++j) {
        accd8(a, xg, Cb[(size_t)nbr[j] * 8 + l8]);
    }
    float inv = 1.f / cntf[node];
    float di = dis[node];
    const float* xop = X + (size_t)node * 64 + l8 * 8;
    const float* xnp = Xn + (size_t)node * 64 + l8 * 8;
    float o[8];
#pragma unroll
    for (int k = 0; k < 8; ++k) {
        float tau = tanh_pos(a[k] * inv);
        float xo = xop[k], xn = xnp[k];
        o[k] = xo + tau * (xn - xo);
    }
    float* xp = X + (size_t)node * 64 + l8 * 8;
    *(float4*)(xp)     = make_float4(o[0], o[1], o[2], o[3]);
    *(float4*)(xp + 4) = make_float4(o[4], o[5], o[6], o[7]);
    uint4 pk;
    pk.x = pack2bf(o[0] * di, o[1] * di);
    pk.y = pack2bf(o[2] * di, o[3] * di);
    pk.z = pack2bf(o[4] * di, o[5] * di);
    pk.w = pack2bf(o[6] * di, o[7] * di);
    ((uint4*)Xbf)[(size_t)node * 8 + l8] = pk;
}

// ---------------- launch ----------------

extern "C" void kernel_launch(void* const* d_in, const int* in_sizes, int n_in,
                              void* d_out, int out_size, void* d_ws, size_t ws_size,
                              hipStream_t stream) {
    const float* x      = (const float*)d_in[0];
    const int*   ei     = (const int*)d_in[1];
    const float* enc_w  = (const float*)d_in[2];
    const float* enc_b  = (const float*)d_in[3];
    const float* conv_w = (const float*)d_in[4];
    const float* conv_b = (const float*)d_in[5];
    const float* gg_w   = (const float*)d_in[6];
    const float* gg_b   = (const float*)d_in[7];
    const float* dec_w  = (const float*)d_in[8];
    const float* dec_b  = (const float*)d_in[9];
    float* out = (float*)d_out;

    const int* src = ei;
    const int* dst = ei + NE;

    char* p = (char*)d_ws;
    auto alloc = [&](size_t bytes) -> void* {
        void* r = (void*)p;
        p += (bytes + 255) & ~(size_t)255;
        return r;
    };
    float* X   = (float*)alloc((size_t)NN * 64 * 4);
    float* Zb  = (float*)alloc((size_t)NN * 64 * 4);           // Z (fp32)
    float* B   = (float*)alloc((size_t)NN * 64 * 4);           // X_ candidate (fp32)
    unsigned short* Xbf = (unsigned short*)alloc((size_t)NN * 64 * 2);  // dis*X, bf16
    unsigned short* Cbf = (unsigned short*)alloc((size_t)NN * 64 * 2);  // xg, bf16
    float* dis  = (float*)alloc((size_t)NN * 4);
    float* cntf = (float*)alloc((size_t)NN * 4);
    int* degin   = (int*)alloc((size_t)NN * 4);
    int* degout  = (int*)alloc((size_t)NN * 4);
    int* off_dst = (int*)alloc((size_t)(NN + 1) * 4);
    int* off_src = (int*)alloc((size_t)(NN + 1) * 4);
    int* hin     = (int*)alloc((size_t)8 * NN * 4);   // per-partition histograms/bases
    int* hout    = (int*)alloc((size_t)8 * NN * 4);
    int* lrin    = (int*)alloc((size_t)NE * 4);       // partition-local ranks
    int* lrout   = (int*)alloc((size_t)NE * 4);
    int* sbd     = (int*)alloc((size_t)NE * 4);   // srcs grouped by dst
    int* dbs     = (int*)alloc((size_t)NE * 4);   // dsts grouped by src
    int* stmp    = (int*)alloc((size_t)2 * NN * 4);  // scan temp
    int* bsum    = (int*)alloc((size_t)2 * SB * 4);  // scan block sums

    hipMemsetAsync(hin, 0, (size_t)8 * NN * 4, stream);
    hipMemsetAsync(hout, 0, (size_t)8 * NN * 4, stream);

    const int NB = (NN + 255) / 256;
    const int NGROUPS = 104;
    count8<<<8 * NGROUPS, 256, 0, stream>>>(src, dst, hin, hout, lrin, lrout, NGROUPS);
    reduce8<<<NB, 256, 0, stream>>>(hin, hout, degin, degout);
    scan_p1<<<2 * SB, 512, 0, stream>>>(degin, degout, stmp, bsum);
    scan_p2<<<1, 128, 0, stream>>>(bsum, off_dst, off_src);
    scan_p3<<<2 * SB, 512, 0, stream>>>(stmp, bsum, off_dst, off_src);
    init_node<<<NB, 256, 0, stream>>>(degin, degout, dis, cntf);
    fill_csr_part<<<8 * NGROUPS, 256, 0, stream>>>(src, dst, off_dst, off_src,
                                                   hin, hout, lrin, lrout,
                                                   sbd, dbs, NGROUPS);

    const int GB = (NN + 63) / 64;                 // 64-row gemm blocks
    const int OB = ((NN * 8) + 255) / 256;         // octet-kernel blocks (8 thr/node)

    // encoder: X = relu(x@enc_w+b); Xbf = bf16(dis*X)
    gemm64b<IND, true, true><<<GB, 256, 0, stream>>>(x, enc_w, enc_b, dis, X, Xbf, NN);

    for (int l = 0; l < DEPTH; ++l) {
        zgather<<<OB, 256, 0, stream>>>(Xbf, off_dst, sbd, dis, Zb);
        gemm64z<false><<<GB, 256, 0, stream>>>(Zb, conv_w, conv_b, B, nullptr, NN);
        gemm64z<true><<<GB, 256, 0, stream>>>(Zb, gg_w, gg_b, nullptr, Cbf, NN);
        gate_update8<<<OB, 256, 0, stream>>>(Cbf, B, X, Xbf, off_src, dbs, cntf, dis);
    }

    // decoder
    gemm64b<NH, true, false><<<GB, 256, 0, stream>>>(X, dec_w, dec_b, nullptr, out, nullptr, NN);
}

// Round 11
// 651.826 us; speedup vs baseline: 1.0512x; 1.0512x over previous
//
#include <hip/hip_runtime.h>
#include <math.h>

#define NN 50000
#define NE 800000
#define IND 256
#define NH 64
#define DEPTH 4
#define PART_DIV 6250   // ceil(NN/8): node partition for XCD-local scatter
#define SB 49           // scan blocks per array (49*1024 >= NN)
#define EPP 100000      // edges per count partition (NE/8)

// ---------------- bf16 helpers ----------------

__device__ __forceinline__ unsigned short f2bf(float f) {
    unsigned int x = __float_as_uint(f);
    unsigned int r = (x + 0x7fffu + ((x >> 16) & 1u)) >> 16;
    return (unsigned short)r;
}
__device__ __forceinline__ unsigned int pack2bf(float lo, float hi) {
    return (unsigned int)f2bf(lo) | ((unsigned int)f2bf(hi) << 16);
}
__device__ __forceinline__ ushort4 f4_to_us4(float4 f) {
    ushort4 u;
    u.x = f2bf(f.x); u.y = f2bf(f.y); u.z = f2bf(f.z); u.w = f2bf(f.w);
    return u;
}
__device__ __forceinline__ void acc8(float* a, uint4 r) {
    a[0] += __uint_as_float(r.x << 16); a[1] += __uint_as_float(r.x & 0xffff0000u);
    a[2] += __uint_as_float(r.y << 16); a[3] += __uint_as_float(r.y & 0xffff0000u);
    a[4] += __uint_as_float(r.z << 16); a[5] += __uint_as_float(r.z & 0xffff0000u);
    a[6] += __uint_as_float(r.w << 16); a[7] += __uint_as_float(r.w & 0xffff0000u);
}
__device__ __forceinline__ void unpack8(float* a, uint4 r) {
    a[0] = __uint_as_float(r.x << 16); a[1] = __uint_as_float(r.x & 0xffff0000u);
    a[2] = __uint_as_float(r.y << 16); a[3] = __uint_as_float(r.y & 0xffff0000u);
    a[4] = __uint_as_float(r.z << 16); a[5] = __uint_as_float(r.z & 0xffff0000u);
    a[6] = __uint_as_float(r.w << 16); a[7] = __uint_as_float(r.w & 0xffff0000u);
}
__device__ __forceinline__ void accd8(float* a, const float* xg, uint4 r) {
    float e;
    e = xg[0] - __uint_as_float(r.x << 16);         a[0] += e * e;
    e = xg[1] - __uint_as_float(r.x & 0xffff0000u); a[1] += e * e;
    e = xg[2] - __uint_as_float(r.y << 16);         a[2] += e * e;
    e = xg[3] - __uint_as_float(r.y & 0xffff0000u); a[3] += e * e;
    e = xg[4] - __uint_as_float(r.z << 16);         a[4] += e * e;
    e = xg[5] - __uint_as_float(r.z & 0xffff0000u); a[5] += e * e;
    e = xg[6] - __uint_as_float(r.w << 16);         a[6] += e * e;
    e = xg[7] - __uint_as_float(r.w & 0xffff0000u); a[7] += e * e;
}
__device__ __forceinline__ float tanh_pos(float x) {
    float t = __expf(-2.f * x);
    return (1.f - t) / (1.f + t);
}

// ---------------- CSR build ----------------

__global__ void count8(const int* __restrict__ src, const int* __restrict__ dst,
                       int* __restrict__ hin, int* __restrict__ hout,
                       int* __restrict__ lrin, int* __restrict__ lrout,
                       int nGroups) {
    int p = blockIdx.x & 7;
    int g = blockIdx.x >> 3;
    int* hi = hin + p * NN;
    int* ho = hout + p * NN;
    for (int i = g * 256 + threadIdx.x; i < EPP; i += nGroups * 256) {
        int e = p * EPP + i;
        int s = src[e], d = dst[e];
        lrin[e]  = atomicAdd(&hi[d], 1);
        lrout[e] = atomicAdd(&ho[s], 1);
    }
}

__global__ void reduce8(int* __restrict__ hin, int* __restrict__ hout,
                        int* __restrict__ degin, int* __restrict__ degout) {
    int i = blockIdx.x * blockDim.x + threadIdx.x;
    if (i >= NN) return;
    int run = 0;
#pragma unroll
    for (int p = 0; p < 8; ++p) {
        int t = hin[p * NN + i]; hin[p * NN + i] = run; run += t;
    }
    degin[i] = run;
    run = 0;
#pragma unroll
    for (int p = 0; p < 8; ++p) {
        int t = hout[p * NN + i]; hout[p * NN + i] = run; run += t;
    }
    degout[i] = run;
}

// -------- parallel exclusive scan, 3 phases, two arrays at once --------
__global__ __launch_bounds__(512) void scan_p1(const int* __restrict__ in0,
                                               const int* __restrict__ in1,
                                               int* __restrict__ tmp,
                                               int* __restrict__ bsum) {
    int a = blockIdx.x / SB;
    int b = blockIdx.x % SB;
    const int* in = a ? in1 : in0;
    int t = threadIdx.x;
    int base = b * 1024 + t * 2;
    int v0 = (base < NN) ? in[base] : 0;
    int v1 = (base + 1 < NN) ? in[base + 1] : 0;
    int v = v0 + v1;
    int x = v;
#pragma unroll
    for (int off = 1; off < 64; off <<= 1) {
        int u = __shfl_up(x, off);
        if ((t & 63) >= off) x += u;
    }
    __shared__ int ws[8];
    int wid = t >> 6, lane = t & 63;
    if (lane == 63) ws[wid] = x;
    __syncthreads();
    if (t == 0) {
        int run = 0;
#pragma unroll
        for (int w = 0; w < 8; ++w) { int s = ws[w]; ws[w] = run; run += s; }
    }
    __syncthreads();
    x += ws[wid];
    int excl = x - v;
    if (base < NN) tmp[a * NN + base] = excl;
    if (base + 1 < NN) tmp[a * NN + base + 1] = excl + v0;
    if (t == 511) bsum[a * SB + b] = x;
}

__global__ __launch_bounds__(128) void scan_p2(int* __restrict__ bsum,
                                               int* __restrict__ out0,
                                               int* __restrict__ out1) {
    int t = threadIdx.x;
    int a = t >> 6, lane = t & 63;
    int v = (lane < SB) ? bsum[a * SB + lane] : 0;
    int x = v;
#pragma unroll
    for (int off = 1; off < 64; off <<= 1) {
        int u = __shfl_up(x, off);
        if (lane >= off) x += u;
    }
    if (lane < SB) bsum[a * SB + lane] = x - v;
    if (lane == SB - 1) {
        if (a == 0) out0[NN] = x; else out1[NN] = x;
    }
}

__global__ __launch_bounds__(512) void scan_p3(const int* __restrict__ tmp,
                                               const int* __restrict__ bsum,
                                               int* __restrict__ out0,
                                               int* __restrict__ out1) {
    int a = blockIdx.x / SB;
    int b = blockIdx.x % SB;
    int* out = a ? out1 : out0;
    int add = bsum[a * SB + b];
    int t = threadIdx.x;
    int base = b * 1024 + t * 2;
    if (base < NN) out[base] = tmp[a * NN + base] + add;
    if (base + 1 < NN) out[base + 1] = tmp[a * NN + base + 1] + add;
}

__global__ void init_node(const int* __restrict__ degin, const int* __restrict__ degout,
                          float* __restrict__ dis, float* __restrict__ cntf) {
    int i = blockIdx.x * blockDim.x + threadIdx.x;
    if (i < NN) {
        dis[i] = rsqrtf((float)(degin[i] + 1));
        int od = degout[i];
        cntf[i] = (float)(od > 0 ? od : 1);
    }
}

__global__ void fill_csr_part(const int* __restrict__ src, const int* __restrict__ dst,
                              const int* __restrict__ off_dst, const int* __restrict__ off_src,
                              const int* __restrict__ hin, const int* __restrict__ hout,
                              const int* __restrict__ lrin, const int* __restrict__ lrout,
                              int* __restrict__ srcs_by_dst, int* __restrict__ dsts_by_src,
                              int nGroups) {
    int q = blockIdx.x & 7;
    int g = blockIdx.x >> 3;
    for (int pe = 0; pe < 8; ++pe) {
        const int* bin = hin + pe * NN;
        const int* bout = hout + pe * NN;
        for (int i = g * 256 + threadIdx.x; i < EPP; i += nGroups * 256) {
            int e = pe * EPP + i;
            int s = src[e], d = dst[e];
            if (d / PART_DIV == q) srcs_by_dst[off_dst[d] + bin[d] + lrin[e]] = s;
            if (s / PART_DIV == q) dsts_by_src[off_src[s] + bout[s] + lrout[e]] = d;
        }
    }
}

// -------- degree bucket sort: equalize octet trip counts within a wave --------
__global__ void bucket_hist(const int* __restrict__ degin, const int* __restrict__ degout,
                            int* __restrict__ ghin, int* __restrict__ ghout) {
    __shared__ int lin[128], lout[128];
    int t = threadIdx.x;
    if (t < 128) { lin[t] = 0; lout[t] = 0; }
    __syncthreads();
    int i = blockIdx.x * 256 + t;
    if (i < NN) {
        atomicAdd(&lin[min(degin[i], 127)], 1);
        atomicAdd(&lout[min(degout[i], 127)], 1);
    }
    __syncthreads();
    if (t < 128) {
        if (lin[t])  atomicAdd(&ghin[t],  lin[t]);
        if (lout[t]) atomicAdd(&ghout[t], lout[t]);
    }
}

__global__ void bucket_scan(const int* __restrict__ ghin, const int* __restrict__ ghout,
                            int* __restrict__ curin, int* __restrict__ curout) {
    __shared__ int a[128], b[128];
    int t = threadIdx.x;
    if (t < 128) a[t] = ghin[t]; else b[t - 128] = ghout[t - 128];
    __syncthreads();
    if (t == 0) { int run = 0; for (int k = 0; k < 128; ++k) { int v = a[k]; a[k] = run; run += v; } }
    if (t == 1) { int run = 0; for (int k = 0; k < 128; ++k) { int v = b[k]; b[k] = run; run += v; } }
    __syncthreads();
    if (t < 128) curin[t] = a[t]; else curout[t - 128] = b[t - 128];
}

__global__ void bucket_scatter(const int* __restrict__ degin, const int* __restrict__ degout,
                               int* __restrict__ curin, int* __restrict__ curout,
                               int* __restrict__ order_in, int* __restrict__ order_out) {
    __shared__ int lin[128], lout[128], basein[128], baseout[128];
    int t = threadIdx.x;
    if (t < 128) { lin[t] = 0; lout[t] = 0; }
    __syncthreads();
    int i = blockIdx.x * 256 + t;
    int bi = 0, bo = 0, ri = 0, ro = 0;
    if (i < NN) {
        bi = min(degin[i], 127);  ri = atomicAdd(&lin[bi], 1);
        bo = min(degout[i], 127); ro = atomicAdd(&lout[bo], 1);
    }
    __syncthreads();
    if (t < 128) {
        basein[t]  = lin[t]  ? atomicAdd(&curin[t],  lin[t])  : 0;
        baseout[t] = lout[t] ? atomicAdd(&curout[t], lout[t]) : 0;
    }
    __syncthreads();
    if (i < NN) {
        order_in[basein[bi] + ri] = i;
        order_out[baseout[bo] + ro] = i;
    }
}

// ---------------- GEMM: [n,K] @ [K,64], 64 rows per block (enc/dec) ----------------
template<int K, bool RELU, bool WSC>
__global__ __launch_bounds__(256) void gemm64b(const float* __restrict__ X,
                                               const float* __restrict__ W,
                                               const float* __restrict__ bias,
                                               const float* __restrict__ rowscale,
                                               float* __restrict__ out,
                                               unsigned short* __restrict__ xsc, int n) {
    __shared__ float Ws[64 * 64];
    __shared__ float Xs[64][68];
    int tid = threadIdx.x;
    int row0 = blockIdx.x * 64;
    int r16 = tid >> 4;
    int cg = tid & 15;
    float4 acc[4];
#pragma unroll
    for (int t = 0; t < 4; ++t) acc[t] = make_float4(0.f, 0.f, 0.f, 0.f);

    for (int kc = 0; kc < K; kc += 64) {
        const float4* W4 = (const float4*)(W + (size_t)kc * 64);
        float4* Ws4 = (float4*)Ws;
#pragma unroll
        for (int t = 0; t < 4; ++t) Ws4[tid + t * 256] = W4[tid + t * 256];
#pragma unroll
        for (int t = 0; t < 4; ++t) {
            int r = r16 + t * 16;
            int grow = row0 + r;
            float4 xv = make_float4(0.f, 0.f, 0.f, 0.f);
            if (grow < n) xv = *(const float4*)(X + (size_t)grow * K + kc + cg * 4);
            Xs[r][cg * 4 + 0] = xv.x; Xs[r][cg * 4 + 1] = xv.y;
            Xs[r][cg * 4 + 2] = xv.z; Xs[r][cg * 4 + 3] = xv.w;
        }
        __syncthreads();
#pragma unroll
        for (int k = 0; k < 64; ++k) {
            float4 w4 = ((const float4*)Ws)[k * 16 + cg];
#pragma unroll
            for (int t = 0; t < 4; ++t) {
                float xv = Xs[r16 + t * 16][k];
                acc[t].x += xv * w4.x; acc[t].y += xv * w4.y;
                acc[t].z += xv * w4.z; acc[t].w += xv * w4.w;
            }
        }
        __syncthreads();
    }

    float4 b4 = ((const float4*)bias)[cg];
#pragma unroll
    for (int t = 0; t < 4; ++t) {
        int row = row0 + r16 + t * 16;
        if (row < n) {
            float4 o;
            o.x = acc[t].x + b4.x; o.y = acc[t].y + b4.y;
            o.z = acc[t].z + b4.z; o.w = acc[t].w + b4.w;
            if (RELU) {
                o.x = fmaxf(o.x, 0.f); o.y = fmaxf(o.y, 0.f);
                o.z = fmaxf(o.z, 0.f); o.w = fmaxf(o.w, 0.f);
            }
            ((float4*)(out + (size_t)row * 64))[cg] = o;
            if (WSC) {
                float s = rowscale[row];
                float4 o2 = make_float4(o.x * s, o.y * s, o.z * s, o.w * s);
                ((ushort4*)(xsc + (size_t)row * 64))[cg] = f4_to_us4(o2);
            }
        }
    }
}

// ---------------- dualgemm32: [n,64] @ [64,128] -> B(bf16) | C(bf16) ----------------
// 32 rows/block, 16 accumulators/thread (same register shape as gemm64b — no
// spill; r6's dualgemm blew up because it used 32 accumulators/thread).
__global__ __launch_bounds__(256) void dualgemm32(
    const float* __restrict__ Z,
    const float* __restrict__ Wb, const float* __restrict__ bb,
    const float* __restrict__ Wc, const float* __restrict__ bc,
    unsigned short* __restrict__ Bbf, unsigned short* __restrict__ Cbf, int n)
{
    __shared__ float W2[64 * 128];
    __shared__ float Xs[32][68];
    int tid = threadIdx.x;
    int row0 = blockIdx.x * 32;
    {
        const float4* wb4 = (const float4*)Wb;
        const float4* wc4 = (const float4*)Wc;
#pragma unroll
        for (int t = 0; t < 4; ++t) {
            int idx = tid + t * 256;           // 0..1023 float4s of a 64x64 mat
            int k = idx >> 4, c = (idx & 15) * 4;
            *(float4*)&W2[k * 128 + c]      = wb4[idx];
            *(float4*)&W2[k * 128 + 64 + c] = wc4[idx];
        }
#pragma unroll
        for (int t = 0; t < 2; ++t) {
            int idx = tid + t * 256;           // 0..511 float4s of 32x64 Z tile
            int r = idx >> 4, c4 = idx & 15;
            int gr = row0 + r;
            float4 xv = make_float4(0.f, 0.f, 0.f, 0.f);
            if (gr < n) xv = *(const float4*)(Z + (size_t)gr * 64 + c4 * 4);
            Xs[r][c4 * 4 + 0] = xv.x; Xs[r][c4 * 4 + 1] = xv.y;
            Xs[r][c4 * 4 + 2] = xv.z; Xs[r][c4 * 4 + 3] = xv.w;
        }
    }
    __syncthreads();

    int r8 = tid >> 5;        // 0..7: rows r8, r8+8, r8+16, r8+24
    int cg = tid & 31;        // 0..31: cols cg*4..cg*4+3 of 128
    float4 acc[4];
#pragma unroll
    for (int t = 0; t < 4; ++t) acc[t] = make_float4(0.f, 0.f, 0.f, 0.f);
#pragma unroll
    for (int k = 0; k < 64; ++k) {
        float4 w4 = *(const float4*)&W2[k * 128 + cg * 4];
#pragma unroll
        for (int t = 0; t < 4; ++t) {
            float xv = Xs[r8 + t * 8][k];
            acc[t].x += xv * w4.x; acc[t].y += xv * w4.y;
            acc[t].z += xv * w4.z; acc[t].w += xv * w4.w;
        }
    }

    float4 bv = (cg < 16) ? ((const float4*)bb)[cg] : ((const float4*)bc)[cg - 16];
#pragma unroll
    for (int t = 0; t < 4; ++t) {
        int row = row0 + r8 + t * 8;
        if (row < n) {
            float4 o;
            o.x = fmaxf(acc[t].x + bv.x, 0.f); o.y = fmaxf(acc[t].y + bv.y, 0.f);
            o.z = fmaxf(acc[t].z + bv.z, 0.f); o.w = fmaxf(acc[t].w + bv.w, 0.f);
            if (cg < 16) ((ushort4*)(Bbf + (size_t)row * 64))[cg]      = f4_to_us4(o);
            else         ((ushort4*)(Cbf + (size_t)row * 64))[cg - 16] = f4_to_us4(o);
        }
    }
}

// ---------------- zgather: node-per-octet, degree-sorted, LDS-free ----------------
__global__ __launch_bounds__(256) void zgather(
    const unsigned short* __restrict__ Xbf,
    const int* __restrict__ off, const int* __restrict__ nbr,
    const float* __restrict__ dis, const int* __restrict__ order,
    float* __restrict__ Z)
{
    int t = blockIdx.x * 256 + threadIdx.x;
    int idx = t >> 3, l8 = t & 7;
    if (idx >= NN) return;
    int node = order[idx];
    const uint4* Xb = (const uint4*)Xbf;
    float a[8];
    unpack8(a, Xb[(size_t)node * 8 + l8]);
    int lo = off[node], hi = off[node + 1];
    int j = lo;
    for (; j + 7 < hi; j += 8) {
        int s0 = nbr[j],     s1 = nbr[j + 1], s2 = nbr[j + 2], s3 = nbr[j + 3];
        int s4 = nbr[j + 4], s5 = nbr[j + 5], s6 = nbr[j + 6], s7 = nbr[j + 7];
        uint4 r0 = Xb[(size_t)s0 * 8 + l8];
        uint4 r1 = Xb[(size_t)s1 * 8 + l8];
        uint4 r2 = Xb[(size_t)s2 * 8 + l8];
        uint4 r3 = Xb[(size_t)s3 * 8 + l8];
        uint4 r4 = Xb[(size_t)s4 * 8 + l8];
        uint4 r5 = Xb[(size_t)s5 * 8 + l8];
        uint4 r6 = Xb[(size_t)s6 * 8 + l8];
        uint4 r7 = Xb[(size_t)s7 * 8 + l8];
        acc8(a, r0); acc8(a, r1); acc8(a, r2); acc8(a, r3);
        acc8(a, r4); acc8(a, r5); acc8(a, r6); acc8(a, r7);
    }
    for (; j + 3 < hi; j += 4) {
        int s0 = nbr[j], s1 = nbr[j + 1], s2 = nbr[j + 2], s3 = nbr[j + 3];
        uint4 r0 = Xb[(size_t)s0 * 8 + l8];
        uint4 r1 = Xb[(size_t)s1 * 8 + l8];
        uint4 r2 = Xb[(size_t)s2 * 8 + l8];
        uint4 r3 = Xb[(size_t)s3 * 8 + l8];
        acc8(a, r0); acc8(a, r1); acc8(a, r2); acc8(a, r3);
    }
    for (; j < hi; ++j) {
        acc8(a, Xb[(size_t)nbr[j] * 8 + l8]);
    }
    float di = dis[node];
    float* zp = Z + (size_t)node * 64 + l8 * 8;
    *(float4*)(zp)     = make_float4(di * a[0], di * a[1], di * a[2], di * a[3]);
    *(float4*)(zp + 4) = make_float4(di * a[4], di * a[5], di * a[6], di * a[7]);
}

// ---------------- gate + convex update: node-per-octet, degree-sorted ----------------
__global__ __launch_bounds__(256) void gate_update8(
    const unsigned short* __restrict__ Cbf, const unsigned short* __restrict__ Xnbf,
    float* __restrict__ X, unsigned short* __restrict__ Xbf,
    const int* __restrict__ off, const int* __restrict__ nbr,
    const float* __restrict__ cntf, const float* __restrict__ dis,
    const int* __restrict__ order)
{
    int t = blockIdx.x * 256 + threadIdx.x;
    int idx = t >> 3, l8 = t & 7;
    if (idx >= NN) return;
    int node = order[idx];
    const uint4* Cb = (const uint4*)Cbf;
    float xg[8];
    unpack8(xg, Cb[(size_t)node * 8 + l8]);
    float a[8] = {0.f, 0.f, 0.f, 0.f, 0.f, 0.f, 0.f, 0.f};
    int lo = off[node], hi = off[node + 1];
    int j = lo;
    for (; j + 7 < hi; j += 8) {
        int d0 = nbr[j],     d1 = nbr[j + 1], d2 = nbr[j + 2], d3 = nbr[j + 3];
        int d4 = nbr[j + 4], d5 = nbr[j + 5], d6 = nbr[j + 6], d7 = nbr[j + 7];
        uint4 r0 = Cb[(size_t)d0 * 8 + l8];
        uint4 r1 = Cb[(size_t)d1 * 8 + l8];
        uint4 r2 = Cb[(size_t)d2 * 8 + l8];
        uint4 r3 = Cb[(size_t)d3 * 8 + l8];
        uint4 r4 = Cb[(size_t)d4 * 8 + l8];
        uint4 r5 = Cb[(size_t)d5 * 8 + l8];
        uint4 r6 = Cb[(size_t)d6 * 8 + l8];
        uint4 r7 = Cb[(size_t)d7 * 8 + l8];
        accd8(a, xg, r0); accd8(a, xg, r1); accd8(a, xg, r2); accd8(a, xg, r3);
        accd8(a, xg, r4); accd8(a, xg, r5); accd8(a, xg, r6); accd8(a, xg, r7);
    }
    for (; j + 3 < hi; j += 4) {
        int d0 = nbr[j], d1 = nbr[j + 1], d2 = nbr[j + 2], d3 = nbr[j + 3];
        uint4 r0 = Cb[(size_t)d0 * 8 + l8];
        uint4 r1 = Cb[(size_t)d1 * 8 + l8];
        uint4 r2 = Cb[(size_t)d2 * 8 + l8];
        uint4 r3 = Cb[(size_t)d3 * 8 + l8];
        accd8(a, xg, r0); accd8(a, xg, r1); accd8(a, xg, r2); accd8(a, xg, r3);
    }
    for (; j < hi; ++j) {
        accd8(a, xg, Cb[(size_t)nbr[j] * 8 + l8]);
    }
    float inv = 1.f / cntf[node];
    float di = dis[node];
    float xn[8];
    unpack8(xn, ((const uint4*)Xnbf)[(size_t)node * 8 + l8]);
    const float* xop = X + (size_t)node * 64 + l8 * 8;
    float o[8];
#pragma unroll
    for (int k = 0; k < 8; ++k) {
        float tau = tanh_pos(a[k] * inv);
        float xo = xop[k];
        o[k] = xo + tau * (xn[k] - xo);
    }
    float* xp = X + (size_t)node * 64 + l8 * 8;
    *(float4*)(xp)     = make_float4(o[0], o[1], o[2], o[3]);
    *(float4*)(xp + 4) = make_float4(o[4], o[5], o[6], o[7]);
    uint4 pk;
    pk.x = pack2bf(o[0] * di, o[1] * di);
    pk.y = pack2bf(o[2] * di, o[3] * di);
    pk.z = pack2bf(o[4] * di, o[5] * di);
    pk.w = pack2bf(o[6] * di, o[7] * di);
    ((uint4*)Xbf)[(size_t)node * 8 + l8] = pk;
}

// ---------------- launch ----------------

extern "C" void kernel_launch(void* const* d_in, const int* in_sizes, int n_in,
                              void* d_out, int out_size, void* d_ws, size_t ws_size,
                              hipStream_t stream) {
    const float* x      = (const float*)d_in[0];
    const int*   ei     = (const int*)d_in[1];
    const float* enc_w  = (const float*)d_in[2];
    const float* enc_b  = (const float*)d_in[3];
    const float* conv_w = (const float*)d_in[4];
    const float* conv_b = (const float*)d_in[5];
    const float* gg_w   = (const float*)d_in[6];
    const float* gg_b   = (const float*)d_in[7];
    const float* dec_w  = (const float*)d_in[8];
    const float* dec_b  = (const float*)d_in[9];
    float* out = (float*)d_out;

    const int* src = ei;
    const int* dst = ei + NE;

    char* p = (char*)d_ws;
    auto alloc = [&](size_t bytes) -> void* {
        void* r = (void*)p;
        p += (bytes + 255) & ~(size_t)255;
        return r;
    };
    float* X   = (float*)alloc((size_t)NN * 64 * 4);
    float* Zb  = (float*)alloc((size_t)NN * 64 * 4);                    // Z (fp32)
    unsigned short* Bbf = (unsigned short*)alloc((size_t)NN * 64 * 2);  // X_ candidate, bf16
    unsigned short* Xbf = (unsigned short*)alloc((size_t)NN * 64 * 2);  // dis*X, bf16
    unsigned short* Cbf = (unsigned short*)alloc((size_t)NN * 64 * 2);  // xg, bf16
    float* dis  = (float*)alloc((size_t)NN * 4);
    float* cntf = (float*)alloc((size_t)NN * 4);
    int* degin   = (int*)alloc((size_t)NN * 4);
    int* degout  = (int*)alloc((size_t)NN * 4);
    int* off_dst = (int*)alloc((size_t)(NN + 1) * 4);
    int* off_src = (int*)alloc((size_t)(NN + 1) * 4);
    int* hin     = (int*)alloc((size_t)8 * NN * 4);
    int* hout    = (int*)alloc((size_t)8 * NN * 4);
    int* lrin    = (int*)alloc((size_t)NE * 4);
    int* lrout   = (int*)alloc((size_t)NE * 4);
    int* sbd     = (int*)alloc((size_t)NE * 4);      // srcs grouped by dst
    int* dbs     = (int*)alloc((size_t)NE * 4);      // dsts grouped by src
    int* stmp    = (int*)alloc((size_t)2 * NN * 4);
    int* bsum    = (int*)alloc((size_t)2 * SB * 4);
    int* order_in  = (int*)alloc((size_t)NN * 4);    // nodes sorted by in-degree
    int* order_out = (int*)alloc((size_t)NN * 4);    // nodes sorted by out-degree
    int* gbins   = (int*)alloc((size_t)512 * 4);     // ghin|ghout|curin|curout
    int* ghin = gbins, *ghout = gbins + 128, *curin = gbins + 256, *curout = gbins + 384;

    hipMemsetAsync(hin, 0, (size_t)8 * NN * 4, stream);
    hipMemsetAsync(hout, 0, (size_t)8 * NN * 4, stream);
    hipMemsetAsync(gbins, 0, (size_t)512 * 4, stream);

    const int NB = (NN + 255) / 256;
    const int NGROUPS = 104;
    count8<<<8 * NGROUPS, 256, 0, stream>>>(src, dst, hin, hout, lrin, lrout, NGROUPS);
    reduce8<<<NB, 256, 0, stream>>>(hin, hout, degin, degout);
    scan_p1<<<2 * SB, 512, 0, stream>>>(degin, degout, stmp, bsum);
    scan_p2<<<1, 128, 0, stream>>>(bsum, off_dst, off_src);
    scan_p3<<<2 * SB, 512, 0, stream>>>(stmp, bsum, off_dst, off_src);
    init_node<<<NB, 256, 0, stream>>>(degin, degout, dis, cntf);
    bucket_hist<<<NB, 256, 0, stream>>>(degin, degout, ghin, ghout);
    bucket_scan<<<1, 256, 0, stream>>>(ghin, ghout, curin, curout);
    bucket_scatter<<<NB, 256, 0, stream>>>(degin, degout, curin, curout,
                                           order_in, order_out);
    fill_csr_part<<<8 * NGROUPS, 256, 0, stream>>>(src, dst, off_dst, off_src,
                                                   hin, hout, lrin, lrout,
                                                   sbd, dbs, NGROUPS);

    const int GB   = (NN + 63) / 64;               // 64-row gemm blocks
    const int GB32 = (NN + 31) / 32;               // dualgemm blocks
    const int OB   = ((NN * 8) + 255) / 256;       // octet-kernel blocks

    // encoder: X = relu(x@enc_w+b); Xbf = bf16(dis*X)
    gemm64b<IND, true, true><<<GB, 256, 0, stream>>>(x, enc_w, enc_b, dis, X, Xbf, NN);

    for (int l = 0; l < DEPTH; ++l) {
        zgather<<<OB, 256, 0, stream>>>(Xbf, off_dst, sbd, dis, order_in, Zb);
        dualgemm32<<<GB32, 256, 0, stream>>>(Zb, conv_w, conv_b, gg_w, gg_b, Bbf, Cbf, NN);
        gate_update8<<<OB, 256, 0, stream>>>(Cbf, Bbf, X, Xbf, off_src, dbs,
                                             cntf, dis, order_out);
    }

    // decoder
    gemm64b<NH, true, false><<<GB, 256, 0, stream>>>(X, dec_w, dec_b, nullptr, out, nullptr, NN);
}

// Round 12
// 625.737 us; speedup vs baseline: 1.0950x; 1.0417x over previous
//
#include <hip/hip_runtime.h>
#include <math.h>

#define NN 50000
#define NE 800000
#define IND 256
#define NH 64
#define DEPTH 4
#define PART_DIV 6250   // ceil(NN/8): node partition for XCD-local scatter stores
#define SB 49           // scan blocks per array (49*1024 >= NN)
#define CEB 782         // count chunks in fused count_enc (= encoder gemm blocks)

// ---------------- bf16 helpers ----------------

__device__ __forceinline__ unsigned short f2bf(float f) {
    unsigned int x = __float_as_uint(f);
    unsigned int r = (x + 0x7fffu + ((x >> 16) & 1u)) >> 16;
    return (unsigned short)r;
}
__device__ __forceinline__ unsigned int pack2bf(float lo, float hi) {
    return (unsigned int)f2bf(lo) | ((unsigned int)f2bf(hi) << 16);
}
__device__ __forceinline__ ushort4 f4_to_us4(float4 f) {
    ushort4 u;
    u.x = f2bf(f.x); u.y = f2bf(f.y); u.z = f2bf(f.z); u.w = f2bf(f.w);
    return u;
}
__device__ __forceinline__ void acc8(float* a, uint4 r) {
    a[0] += __uint_as_float(r.x << 16); a[1] += __uint_as_float(r.x & 0xffff0000u);
    a[2] += __uint_as_float(r.y << 16); a[3] += __uint_as_float(r.y & 0xffff0000u);
    a[4] += __uint_as_float(r.z << 16); a[5] += __uint_as_float(r.z & 0xffff0000u);
    a[6] += __uint_as_float(r.w << 16); a[7] += __uint_as_float(r.w & 0xffff0000u);
}
__device__ __forceinline__ void unpack8(float* a, uint4 r) {
    a[0] = __uint_as_float(r.x << 16); a[1] = __uint_as_float(r.x & 0xffff0000u);
    a[2] = __uint_as_float(r.y << 16); a[3] = __uint_as_float(r.y & 0xffff0000u);
    a[4] = __uint_as_float(r.z << 16); a[5] = __uint_as_float(r.z & 0xffff0000u);
    a[6] = __uint_as_float(r.w << 16); a[7] = __uint_as_float(r.w & 0xffff0000u);
}
__device__ __forceinline__ void accd8(float* a, const float* xg, uint4 r) {
    float e;
    e = xg[0] - __uint_as_float(r.x << 16);         a[0] += e * e;
    e = xg[1] - __uint_as_float(r.x & 0xffff0000u); a[1] += e * e;
    e = xg[2] - __uint_as_float(r.y << 16);         a[2] += e * e;
    e = xg[3] - __uint_as_float(r.y & 0xffff0000u); a[3] += e * e;
    e = xg[4] - __uint_as_float(r.z << 16);         a[4] += e * e;
    e = xg[5] - __uint_as_float(r.z & 0xffff0000u); a[5] += e * e;
    e = xg[6] - __uint_as_float(r.w << 16);         a[6] += e * e;
    e = xg[7] - __uint_as_float(r.w & 0xffff0000u); a[7] += e * e;
}
__device__ __forceinline__ float tanh_pos(float x) {
    float t = __expf(-2.f * x);
    return (1.f - t) / (1.f + t);
}

// ---------------- fused CSR count + encoder GEMM ----------------
// count8 is atomic-fabric-bound (63 µs at VALUBusy 0.3%, occ 30% — r10/r11
// counters, partitioning-invariant). The encoder GEMM has no CSR dependency
// and uses the idle VALU/LDS pipes. Interleave block types (even=count chunk,
// odd=gemm tile) so the dispatcher co-resides both on every CU.
__global__ __launch_bounds__(256) void count_enc(
    const int* __restrict__ src, const int* __restrict__ dst,
    int* __restrict__ degin, int* __restrict__ degout,
    int* __restrict__ rank_in, int* __restrict__ rank_out,
    const float* __restrict__ x, const float* __restrict__ enc_w,
    const float* __restrict__ enc_b, float* __restrict__ X)
{
    __shared__ float Ws[64 * 64];
    __shared__ float Xs[64][68];
    int bid = blockIdx.x;
    if ((bid & 1) == 0) {
        // ---- count branch: chunk c of CEB, grid-stride over edges ----
        int c = bid >> 1;
        for (int e = c * 256 + threadIdx.x; e < NE; e += CEB * 256) {
            int s = src[e], d = dst[e];
            rank_in[e]  = atomicAdd(&degin[d], 1);   // return value = rank
            rank_out[e] = atomicAdd(&degout[s], 1);
        }
        return;
    }
    // ---- encoder gemm branch: 64 rows, K=256 ----
    int tid = threadIdx.x;
    int row0 = (bid >> 1) * 64;
    int r16 = tid >> 4;
    int cg = tid & 15;
    float4 acc[4];
#pragma unroll
    for (int t = 0; t < 4; ++t) acc[t] = make_float4(0.f, 0.f, 0.f, 0.f);

    for (int kc = 0; kc < IND; kc += 64) {
        const float4* W4 = (const float4*)(enc_w + (size_t)kc * 64);
        float4* Ws4 = (float4*)Ws;
#pragma unroll
        for (int t = 0; t < 4; ++t) Ws4[tid + t * 256] = W4[tid + t * 256];
#pragma unroll
        for (int t = 0; t < 4; ++t) {
            int r = r16 + t * 16;
            int grow = row0 + r;
            float4 xv = make_float4(0.f, 0.f, 0.f, 0.f);
            if (grow < NN) xv = *(const float4*)(x + (size_t)grow * IND + kc + cg * 4);
            Xs[r][cg * 4 + 0] = xv.x; Xs[r][cg * 4 + 1] = xv.y;
            Xs[r][cg * 4 + 2] = xv.z; Xs[r][cg * 4 + 3] = xv.w;
        }
        __syncthreads();
#pragma unroll
        for (int k = 0; k < 64; ++k) {
            float4 w4 = ((const float4*)Ws)[k * 16 + cg];
#pragma unroll
            for (int t = 0; t < 4; ++t) {
                float xv = Xs[r16 + t * 16][k];
                acc[t].x += xv * w4.x; acc[t].y += xv * w4.y;
                acc[t].z += xv * w4.z; acc[t].w += xv * w4.w;
            }
        }
        __syncthreads();
    }
    float4 b4 = ((const float4*)enc_b)[cg];
#pragma unroll
    for (int t = 0; t < 4; ++t) {
        int row = row0 + r16 + t * 16;
        if (row < NN) {
            float4 o;
            o.x = fmaxf(acc[t].x + b4.x, 0.f); o.y = fmaxf(acc[t].y + b4.y, 0.f);
            o.z = fmaxf(acc[t].z + b4.z, 0.f); o.w = fmaxf(acc[t].w + b4.w, 0.f);
            ((float4*)(X + (size_t)row * 64))[cg] = o;
        }
    }
}

// -------- parallel exclusive scan, 3 phases, two arrays at once --------
__global__ __launch_bounds__(512) void scan_p1(const int* __restrict__ in0,
                                               const int* __restrict__ in1,
                                               int* __restrict__ tmp,
                                               int* __restrict__ bsum) {
    int a = blockIdx.x / SB;
    int b = blockIdx.x % SB;
    const int* in = a ? in1 : in0;
    int t = threadIdx.x;
    int base = b * 1024 + t * 2;
    int v0 = (base < NN) ? in[base] : 0;
    int v1 = (base + 1 < NN) ? in[base + 1] : 0;
    int v = v0 + v1;
    int x = v;
#pragma unroll
    for (int off = 1; off < 64; off <<= 1) {
        int u = __shfl_up(x, off);
        if ((t & 63) >= off) x += u;
    }
    __shared__ int ws[8];
    int wid = t >> 6, lane = t & 63;
    if (lane == 63) ws[wid] = x;
    __syncthreads();
    if (t == 0) {
        int run = 0;
#pragma unroll
        for (int w = 0; w < 8; ++w) { int s = ws[w]; ws[w] = run; run += s; }
    }
    __syncthreads();
    x += ws[wid];
    int excl = x - v;
    if (base < NN) tmp[a * NN + base] = excl;
    if (base + 1 < NN) tmp[a * NN + base + 1] = excl + v0;
    if (t == 511) bsum[a * SB + b] = x;
}

__global__ __launch_bounds__(128) void scan_p2(int* __restrict__ bsum,
                                               int* __restrict__ out0,
                                               int* __restrict__ out1) {
    int t = threadIdx.x;
    int a = t >> 6, lane = t & 63;
    int v = (lane < SB) ? bsum[a * SB + lane] : 0;
    int x = v;
#pragma unroll
    for (int off = 1; off < 64; off <<= 1) {
        int u = __shfl_up(x, off);
        if (lane >= off) x += u;
    }
    if (lane < SB) bsum[a * SB + lane] = x - v;
    if (lane == SB - 1) {
        if (a == 0) out0[NN] = x; else out1[NN] = x;
    }
}

__global__ __launch_bounds__(512) void scan_p3(const int* __restrict__ tmp,
                                               const int* __restrict__ bsum,
                                               int* __restrict__ out0,
                                               int* __restrict__ out1) {
    int a = blockIdx.x / SB;
    int b = blockIdx.x % SB;
    int* out = a ? out1 : out0;
    int add = bsum[a * SB + b];
    int t = threadIdx.x;
    int base = b * 1024 + t * 2;
    if (base < NN) out[base] = tmp[a * NN + base] + add;
    if (base + 1 < NN) out[base + 1] = tmp[a * NN + base + 1] + add;
}

// ---------------- init + Xbf pack (octet layout) ----------------
// dis/cntf per node; Xbf = bf16(dis*X). Encoder can no longer pack Xbf
// because dis depends on the degrees being counted concurrently.
__global__ __launch_bounds__(256) void init_pack(
    const int* __restrict__ degin, const int* __restrict__ degout,
    float* __restrict__ dis, float* __restrict__ cntf,
    const float* __restrict__ X, unsigned short* __restrict__ Xbf)
{
    int t = blockIdx.x * 256 + threadIdx.x;
    int node = t >> 3, l8 = t & 7;
    if (node >= NN) return;
    float di = rsqrtf((float)(degin[node] + 1));
    if (l8 == 0) {
        dis[node] = di;
        int od = degout[node];
        cntf[node] = (float)(od > 0 ? od : 1);
    }
    const float4* xp = (const float4*)(X + (size_t)node * 64 + l8 * 8);
    float4 v0 = xp[0], v1 = xp[1];
    uint4 pk;
    pk.x = pack2bf(v0.x * di, v0.y * di);
    pk.y = pack2bf(v0.z * di, v0.w * di);
    pk.z = pack2bf(v1.x * di, v1.y * di);
    pk.w = pack2bf(v1.z * di, v1.w * di);
    ((uint4*)Xbf)[(size_t)node * 8 + l8] = pk;
}

// -------- degree bucket sort: equalize octet trip counts within a wave --------
__global__ void bucket_hist(const int* __restrict__ degin, const int* __restrict__ degout,
                            int* __restrict__ ghin, int* __restrict__ ghout) {
    __shared__ int lin[128], lout[128];
    int t = threadIdx.x;
    if (t < 128) { lin[t] = 0; lout[t] = 0; }
    __syncthreads();
    int i = blockIdx.x * 256 + t;
    if (i < NN) {
        atomicAdd(&lin[min(degin[i], 127)], 1);
        atomicAdd(&lout[min(degout[i], 127)], 1);
    }
    __syncthreads();
    if (t < 128) {
        if (lin[t])  atomicAdd(&ghin[t],  lin[t]);
        if (lout[t]) atomicAdd(&ghout[t], lout[t]);
    }
}

__global__ void bucket_scan(const int* __restrict__ ghin, const int* __restrict__ ghout,
                            int* __restrict__ curin, int* __restrict__ curout) {
    __shared__ int a[128], b[128];
    int t = threadIdx.x;
    if (t < 128) a[t] = ghin[t]; else b[t - 128] = ghout[t - 128];
    __syncthreads();
    if (t == 0) { int run = 0; for (int k = 0; k < 128; ++k) { int v = a[k]; a[k] = run; run += v; } }
    if (t == 1) { int run = 0; for (int k = 0; k < 128; ++k) { int v = b[k]; b[k] = run; run += v; } }
    __syncthreads();
    if (t < 128) curin[t] = a[t]; else curout[t - 128] = b[t - 128];
}

__global__ void bucket_scatter(const int* __restrict__ degin, const int* __restrict__ degout,
                               int* __restrict__ curin, int* __restrict__ curout,
                               int* __restrict__ order_in, int* __restrict__ order_out) {
    __shared__ int lin[128], lout[128], basein[128], baseout[128];
    int t = threadIdx.x;
    if (t < 128) { lin[t] = 0; lout[t] = 0; }
    __syncthreads();
    int i = blockIdx.x * 256 + t;
    int bi = 0, bo = 0, ri = 0, ro = 0;
    if (i < NN) {
        bi = min(degin[i], 127);  ri = atomicAdd(&lin[bi], 1);
        bo = min(degout[i], 127); ro = atomicAdd(&lout[bo], 1);
    }
    __syncthreads();
    if (t < 128) {
        basein[t]  = lin[t]  ? atomicAdd(&curin[t],  lin[t])  : 0;
        baseout[t] = lout[t] ? atomicAdd(&curout[t], lout[t]) : 0;
    }
    __syncthreads();
    if (i < NN) {
        order_in[basein[bi] + ri] = i;
        order_out[baseout[bo] + ro] = i;
    }
}

// Atomic-free, store-partitioned CSR scatter: position = offset + rank.
__global__ void fill_csr_part(const int* __restrict__ src, const int* __restrict__ dst,
                              const int* __restrict__ off_dst, const int* __restrict__ off_src,
                              const int* __restrict__ rank_in, const int* __restrict__ rank_out,
                              int* __restrict__ srcs_by_dst, int* __restrict__ dsts_by_src,
                              int nGroups) {
    int q = blockIdx.x & 7;
    int g = blockIdx.x >> 3;
    for (int e = g * 256 + threadIdx.x; e < NE; e += nGroups * 256) {
        int s = src[e], d = dst[e];
        if (d / PART_DIV == q) srcs_by_dst[off_dst[d] + rank_in[e]] = s;
        if (s / PART_DIV == q) dsts_by_src[off_src[s] + rank_out[e]] = d;
    }
}

// ---------------- GEMM: [n,K] @ [K,64] + relu (decoder) ----------------
template<int K>
__global__ __launch_bounds__(256) void gemm64b(const float* __restrict__ X,
                                               const float* __restrict__ W,
                                               const float* __restrict__ bias,
                                               float* __restrict__ out, int n) {
    __shared__ float Ws[64 * 64];
    __shared__ float Xs[64][68];
    int tid = threadIdx.x;
    int row0 = blockIdx.x * 64;
    int r16 = tid >> 4;
    int cg = tid & 15;
    float4 acc[4];
#pragma unroll
    for (int t = 0; t < 4; ++t) acc[t] = make_float4(0.f, 0.f, 0.f, 0.f);

    for (int kc = 0; kc < K; kc += 64) {
        const float4* W4 = (const float4*)(W + (size_t)kc * 64);
        float4* Ws4 = (float4*)Ws;
#pragma unroll
        for (int t = 0; t < 4; ++t) Ws4[tid + t * 256] = W4[tid + t * 256];
#pragma unroll
        for (int t = 0; t < 4; ++t) {
            int r = r16 + t * 16;
            int grow = row0 + r;
            float4 xv = make_float4(0.f, 0.f, 0.f, 0.f);
            if (grow < n) xv = *(const float4*)(X + (size_t)grow * K + kc + cg * 4);
            Xs[r][cg * 4 + 0] = xv.x; Xs[r][cg * 4 + 1] = xv.y;
            Xs[r][cg * 4 + 2] = xv.z; Xs[r][cg * 4 + 3] = xv.w;
        }
        __syncthreads();
#pragma unroll
        for (int k = 0; k < 64; ++k) {
            float4 w4 = ((const float4*)Ws)[k * 16 + cg];
#pragma unroll
            for (int t = 0; t < 4; ++t) {
                float xv = Xs[r16 + t * 16][k];
                acc[t].x += xv * w4.x; acc[t].y += xv * w4.y;
                acc[t].z += xv * w4.z; acc[t].w += xv * w4.w;
            }
        }
        __syncthreads();
    }

    float4 b4 = ((const float4*)bias)[cg];
#pragma unroll
    for (int t = 0; t < 4; ++t) {
        int row = row0 + r16 + t * 16;
        if (row < n) {
            float4 o;
            o.x = fmaxf(acc[t].x + b4.x, 0.f); o.y = fmaxf(acc[t].y + b4.y, 0.f);
            o.z = fmaxf(acc[t].z + b4.z, 0.f); o.w = fmaxf(acc[t].w + b4.w, 0.f);
            ((float4*)(out + (size_t)row * 64))[cg] = o;
        }
    }
}

// ---------------- dualgemm32: [n,64] @ [64,128] -> B(bf16) | C(bf16) ----------------
// 32 rows/block, 16 accumulators/thread (gemm64b register shape — no spill).
__global__ __launch_bounds__(256) void dualgemm32(
    const float* __restrict__ Z,
    const float* __restrict__ Wb, const float* __restrict__ bb,
    const float* __restrict__ Wc, const float* __restrict__ bc,
    unsigned short* __restrict__ Bbf, unsigned short* __restrict__ Cbf, int n)
{
    __shared__ float W2[64 * 128];
    __shared__ float Xs[32][68];
    int tid = threadIdx.x;
    int row0 = blockIdx.x * 32;
    {
        const float4* wb4 = (const float4*)Wb;
        const float4* wc4 = (const float4*)Wc;
#pragma unroll
        for (int t = 0; t < 4; ++t) {
            int idx = tid + t * 256;
            int k = idx >> 4, c = (idx & 15) * 4;
            *(float4*)&W2[k * 128 + c]      = wb4[idx];
            *(float4*)&W2[k * 128 + 64 + c] = wc4[idx];
        }
#pragma unroll
        for (int t = 0; t < 2; ++t) {
            int idx = tid + t * 256;
            int r = idx >> 4, c4 = idx & 15;
            int gr = row0 + r;
            float4 xv = make_float4(0.f, 0.f, 0.f, 0.f);
            if (gr < n) xv = *(const float4*)(Z + (size_t)gr * 64 + c4 * 4);
            Xs[r][c4 * 4 + 0] = xv.x; Xs[r][c4 * 4 + 1] = xv.y;
            Xs[r][c4 * 4 + 2] = xv.z; Xs[r][c4 * 4 + 3] = xv.w;
        }
    }
    __syncthreads();

    int r8 = tid >> 5;
    int cg = tid & 31;
    float4 acc[4];
#pragma unroll
    for (int t = 0; t < 4; ++t) acc[t] = make_float4(0.f, 0.f, 0.f, 0.f);
#pragma unroll
    for (int k = 0; k < 64; ++k) {
        float4 w4 = *(const float4*)&W2[k * 128 + cg * 4];
#pragma unroll
        for (int t = 0; t < 4; ++t) {
            float xv = Xs[r8 + t * 8][k];
            acc[t].x += xv * w4.x; acc[t].y += xv * w4.y;
            acc[t].z += xv * w4.z; acc[t].w += xv * w4.w;
        }
    }

    float4 bv = (cg < 16) ? ((const float4*)bb)[cg] : ((const float4*)bc)[cg - 16];
#pragma unroll
    for (int t = 0; t < 4; ++t) {
        int row = row0 + r8 + t * 8;
        if (row < n) {
            float4 o;
            o.x = fmaxf(acc[t].x + bv.x, 0.f); o.y = fmaxf(acc[t].y + bv.y, 0.f);
            o.z = fmaxf(acc[t].z + bv.z, 0.f); o.w = fmaxf(acc[t].w + bv.w, 0.f);
            if (cg < 16) ((ushort4*)(Bbf + (size_t)row * 64))[cg]      = f4_to_us4(o);
            else         ((ushort4*)(Cbf + (size_t)row * 64))[cg - 16] = f4_to_us4(o);
        }
    }
}

// ---------------- zgather: node-per-octet, degree-sorted, LDS-free ----------------
__global__ __launch_bounds__(256) void zgather(
    const unsigned short* __restrict__ Xbf,
    const int* __restrict__ off, const int* __restrict__ nbr,
    const float* __restrict__ dis, const int* __restrict__ order,
    float* __restrict__ Z)
{
    int t = blockIdx.x * 256 + threadIdx.x;
    int idx = t >> 3, l8 = t & 7;
    if (idx >= NN) return;
    int node = order[idx];
    const uint4* Xb = (const uint4*)Xbf;
    float a[8];
    unpack8(a, Xb[(size_t)node * 8 + l8]);
    int lo = off[node], hi = off[node + 1];
    int j = lo;
    for (; j + 7 < hi; j += 8) {
        int s0 = nbr[j],     s1 = nbr[j + 1], s2 = nbr[j + 2], s3 = nbr[j + 3];
        int s4 = nbr[j + 4], s5 = nbr[j + 5], s6 = nbr[j + 6], s7 = nbr[j + 7];
        uint4 r0 = Xb[(size_t)s0 * 8 + l8];
        uint4 r1 = Xb[(size_t)s1 * 8 + l8];
        uint4 r2 = Xb[(size_t)s2 * 8 + l8];
        uint4 r3 = Xb[(size_t)s3 * 8 + l8];
        uint4 r4 = Xb[(size_t)s4 * 8 + l8];
        uint4 r5 = Xb[(size_t)s5 * 8 + l8];
        uint4 r6 = Xb[(size_t)s6 * 8 + l8];
        uint4 r7 = Xb[(size_t)s7 * 8 + l8];
        acc8(a, r0); acc8(a, r1); acc8(a, r2); acc8(a, r3);
        acc8(a, r4); acc8(a, r5); acc8(a, r6); acc8(a, r7);
    }
    for (; j + 3 < hi; j += 4) {
        int s0 = nbr[j], s1 = nbr[j + 1], s2 = nbr[j + 2], s3 = nbr[j + 3];
        uint4 r0 = Xb[(size_t)s0 * 8 + l8];
        uint4 r1 = Xb[(size_t)s1 * 8 + l8];
        uint4 r2 = Xb[(size_t)s2 * 8 + l8];
        uint4 r3 = Xb[(size_t)s3 * 8 + l8];
        acc8(a, r0); acc8(a, r1); acc8(a, r2); acc8(a, r3);
    }
    for (; j < hi; ++j) {
        acc8(a, Xb[(size_t)nbr[j] * 8 + l8]);
    }
    float di = dis[node];
    float* zp = Z + (size_t)node * 64 + l8 * 8;
    *(float4*)(zp)     = make_float4(di * a[0], di * a[1], di * a[2], di * a[3]);
    *(float4*)(zp + 4) = make_float4(di * a[4], di * a[5], di * a[6], di * a[7]);
}

// ---------------- gate + convex update: node-per-octet, degree-sorted ----------------
__global__ __launch_bounds__(256) void gate_update8(
    const unsigned short* __restrict__ Cbf, const unsigned short* __restrict__ Xnbf,
    float* __restrict__ X, unsigned short* __restrict__ Xbf,
    const int* __restrict__ off, const int* __restrict__ nbr,
    const float* __restrict__ cntf, const float* __restrict__ dis,
    const int* __restrict__ order)
{
    int t = blockIdx.x * 256 + threadIdx.x;
    int idx = t >> 3, l8 = t & 7;
    if (idx >= NN) return;
    int node = order[idx];
    const uint4* Cb = (const uint4*)Cbf;
    float xg[8];
    unpack8(xg, Cb[(size_t)node * 8 + l8]);
    float a[8] = {0.f, 0.f, 0.f, 0.f, 0.f, 0.f, 0.f, 0.f};
    int lo = off[node], hi = off[node + 1];
    int j = lo;
    for (; j + 7 < hi; j += 8) {
        int d0 = nbr[j],     d1 = nbr[j + 1], d2 = nbr[j + 2], d3 = nbr[j + 3];
        int d4 = nbr[j + 4], d5 = nbr[j + 5], d6 = nbr[j + 6], d7 = nbr[j + 7];
        uint4 r0 = Cb[(size_t)d0 * 8 + l8];
        uint4 r1 = Cb[(size_t)d1 * 8 + l8];
        uint4 r2 = Cb[(size_t)d2 * 8 + l8];
        uint4 r3 = Cb[(size_t)d3 * 8 + l8];
        uint4 r4 = Cb[(size_t)d4 * 8 + l8];
        uint4 r5 = Cb[(size_t)d5 * 8 + l8];
        uint4 r6 = Cb[(size_t)d6 * 8 + l8];
        uint4 r7 = Cb[(size_t)d7 * 8 + l8];
        accd8(a, xg, r0); accd8(a, xg, r1); accd8(a, xg, r2); accd8(a, xg, r3);
        accd8(a, xg, r4); accd8(a, xg, r5); accd8(a, xg, r6); accd8(a, xg, r7);
    }
    for (; j + 3 < hi; j += 4) {
        int d0 = nbr[j], d1 = nbr[j + 1], d2 = nbr[j + 2], d3 = nbr[j + 3];
        uint4 r0 = Cb[(size_t)d0 * 8 + l8];
        uint4 r1 = Cb[(size_t)d1 * 8 + l8];
        uint4 r2 = Cb[(size_t)d2 * 8 + l8];
        uint4 r3 = Cb[(size_t)d3 * 8 + l8];
        accd8(a, xg, r0); accd8(a, xg, r1); accd8(a, xg, r2); accd8(a, xg, r3);
    }
    for (; j < hi; ++j) {
        accd8(a, xg, Cb[(size_t)nbr[j] * 8 + l8]);
    }
    float inv = 1.f / cntf[node];
    float di = dis[node];
    float xn[8];
    unpack8(xn, ((const uint4*)Xnbf)[(size_t)node * 8 + l8]);
    const float* xop = X + (size_t)node * 64 + l8 * 8;
    float o[8];
#pragma unroll
    for (int k = 0; k < 8; ++k) {
        float tau = tanh_pos(a[k] * inv);
        float xo = xop[k];
        o[k] = xo + tau * (xn[k] - xo);
    }
    float* xp = X + (size_t)node * 64 + l8 * 8;
    *(float4*)(xp)     = make_float4(o[0], o[1], o[2], o[3]);
    *(float4*)(xp + 4) = make_float4(o[4], o[5], o[6], o[7]);
    uint4 pk;
    pk.x = pack2bf(o[0] * di, o[1] * di);
    pk.y = pack2bf(o[2] * di, o[3] * di);
    pk.z = pack2bf(o[4] * di, o[5] * di);
    pk.w = pack2bf(o[6] * di, o[7] * di);
    ((uint4*)Xbf)[(size_t)node * 8 + l8] = pk;
}

// ---------------- launch ----------------

extern "C" void kernel_launch(void* const* d_in, const int* in_sizes, int n_in,
                              void* d_out, int out_size, void* d_ws, size_t ws_size,
                              hipStream_t stream) {
    const float* x      = (const float*)d_in[0];
    const int*   ei     = (const int*)d_in[1];
    const float* enc_w  = (const float*)d_in[2];
    const float* enc_b  = (const float*)d_in[3];
    const float* conv_w = (const float*)d_in[4];
    const float* conv_b = (const float*)d_in[5];
    const float* gg_w   = (const float*)d_in[6];
    const float* gg_b   = (const float*)d_in[7];
    const float* dec_w  = (const float*)d_in[8];
    const float* dec_b  = (const float*)d_in[9];
    float* out = (float*)d_out;

    const int* src = ei;
    const int* dst = ei + NE;

    char* p = (char*)d_ws;
    auto alloc = [&](size_t bytes) -> void* {
        void* r = (void*)p;
        p += (bytes + 255) & ~(size_t)255;
        return r;
    };
    float* X   = (float*)alloc((size_t)NN * 64 * 4);
    float* Zb  = (float*)alloc((size_t)NN * 64 * 4);                    // Z (fp32)
    unsigned short* Bbf = (unsigned short*)alloc((size_t)NN * 64 * 2);  // X_ candidate, bf16
    unsigned short* Xbf = (unsigned short*)alloc((size_t)NN * 64 * 2);  // dis*X, bf16
    unsigned short* Cbf = (unsigned short*)alloc((size_t)NN * 64 * 2);  // xg, bf16
    float* dis  = (float*)alloc((size_t)NN * 4);
    float* cntf = (float*)alloc((size_t)NN * 4);
    int* degin   = (int*)alloc((size_t)NN * 4);
    int* degout  = (int*)alloc((size_t)NN * 4);
    int* off_dst = (int*)alloc((size_t)(NN + 1) * 4);
    int* off_src = (int*)alloc((size_t)(NN + 1) * 4);
    int* rank_in  = (int*)alloc((size_t)NE * 4);
    int* rank_out = (int*)alloc((size_t)NE * 4);
    int* sbd     = (int*)alloc((size_t)NE * 4);      // srcs grouped by dst
    int* dbs     = (int*)alloc((size_t)NE * 4);      // dsts grouped by src
    int* stmp    = (int*)alloc((size_t)2 * NN * 4);
    int* bsum    = (int*)alloc((size_t)2 * SB * 4);
    int* order_in  = (int*)alloc((size_t)NN * 4);
    int* order_out = (int*)alloc((size_t)NN * 4);
    int* gbins   = (int*)alloc((size_t)512 * 4);
    int* ghin = gbins, *ghout = gbins + 128, *curin = gbins + 256, *curout = gbins + 384;

    hipMemsetAsync(degin, 0, (size_t)NN * 4, stream);
    hipMemsetAsync(degout, 0, (size_t)NN * 4, stream);
    hipMemsetAsync(gbins, 0, (size_t)512 * 4, stream);

    const int NB = (NN + 255) / 256;
    const int OB = ((NN * 8) + 255) / 256;         // octet-kernel blocks
    const int NGROUPS = 104;

    // fused CSR-count + encoder GEMM (interleaved block types)
    count_enc<<<2 * CEB, 256, 0, stream>>>(src, dst, degin, degout,
                                           rank_in, rank_out, x, enc_w, enc_b, X);
    scan_p1<<<2 * SB, 512, 0, stream>>>(degin, degout, stmp, bsum);
    scan_p2<<<1, 128, 0, stream>>>(bsum, off_dst, off_src);
    scan_p3<<<2 * SB, 512, 0, stream>>>(stmp, bsum, off_dst, off_src);
    init_pack<<<OB, 256, 0, stream>>>(degin, degout, dis, cntf, X, Xbf);
    bucket_hist<<<NB, 256, 0, stream>>>(degin, degout, ghin, ghout);
    bucket_scan<<<1, 256, 0, stream>>>(ghin, ghout, curin, curout);
    bucket_scatter<<<NB, 256, 0, stream>>>(degin, degout, curin, curout,
                                           order_in, order_out);
    fill_csr_part<<<8 * NGROUPS, 256, 0, stream>>>(src, dst, off_dst, off_src,
                                                   rank_in, rank_out, sbd, dbs, NGROUPS);

    const int GB   = (NN + 63) / 64;               // 64-row gemm blocks
    const int GB32 = (NN + 31) / 32;               // dualgemm blocks

    for (int l = 0; l < DEPTH; ++l) {
        zgather<<<OB, 256, 0, stream>>>(Xbf, off_dst, sbd, dis, order_in, Zb);
        dualgemm32<<<GB32, 256, 0, stream>>>(Zb, conv_w, conv_b, gg_w, gg_b, Bbf, Cbf, NN);
        gate_update8<<<OB, 256, 0, stream>>>(Cbf, Bbf, X, Xbf, off_src, dbs,
                                             cntf, dis, order_out);
    }

    // decoder
    gemm64b<NH><<<GB, 256, 0, stream>>>(X, dec_w, dec_b, out, NN);
}